// Round 7
// baseline (2395.747 us; speedup 1.0000x reference)
//
#include <hip/hip_runtime.h>
#include <hip/hip_bf16.h>
#include <cstdint>
#include <cstddef>

#define B_ 64
#define T_ 2048
#define D_ 256
#define H_ 256

// ---------------------------------------------------------------------------
// Kernel 1: projection GEMM  xp[b,t,:] = x[b,t,:] @ Wxh + b  (fp32 — the
// recurrence is chaotic: fp32 reorder noise alone gives absmax ~4e-3, i.e.
// amplification ~1e4. Any bf16/MFMA path would blow the 2e-2 threshold.)
// Written IN PLACE into d_out; recurrence overwrites each row after use.
// ---------------------------------------------------------------------------
#define PM 128
#define PN 128
#define PK 32

__global__ __launch_bounds__(256) void proj_kernel(const float* __restrict__ x,
                                                   const float* __restrict__ Wxh,
                                                   const float* __restrict__ bias,
                                                   float* __restrict__ xp) {
    __shared__ float As[PK][PM + 4];
    __shared__ float Bs[PK][PN + 4];
    const int tid = threadIdx.x;
    const int M0 = blockIdx.x * PM;
    const int N0 = blockIdx.y * PN;
    const int tr = tid >> 4;
    const int tc = tid & 15;

    float acc[8][8];
#pragma unroll
    for (int i = 0; i < 8; ++i)
#pragma unroll
        for (int j = 0; j < 8; ++j) acc[i][j] = 0.f;

    const int fA = tid & 7;
    const int rA = tid >> 3;
    const int kB = tid >> 3;
    const int fB = tid & 7;

    for (int kt = 0; kt < D_; kt += PK) {
#pragma unroll
        for (int i = 0; i < 4; ++i) {
            const int r = rA + i * 32;
            const float4 v = *(const float4*)&x[(size_t)(M0 + r) * D_ + kt + fA * 4];
            As[fA * 4 + 0][r] = v.x;
            As[fA * 4 + 1][r] = v.y;
            As[fA * 4 + 2][r] = v.z;
            As[fA * 4 + 3][r] = v.w;
        }
#pragma unroll
        for (int i = 0; i < 4; ++i) {
            const int c4 = fB + i * 8;
            const float4 v = *(const float4*)&Wxh[(size_t)(kt + kB) * H_ + N0 + c4 * 4];
            *(float4*)&Bs[kB][c4 * 4] = v;
        }
        __syncthreads();
#pragma unroll
        for (int k = 0; k < PK; ++k) {
            float a[8], bv[8];
            *(float4*)&a[0] = *(const float4*)&As[k][tr * 8];
            *(float4*)&a[4] = *(const float4*)&As[k][tr * 8 + 4];
            *(float4*)&bv[0] = *(const float4*)&Bs[k][tc * 8];
            *(float4*)&bv[4] = *(const float4*)&Bs[k][tc * 8 + 4];
#pragma unroll
            for (int i = 0; i < 8; ++i)
#pragma unroll
                for (int j = 0; j < 8; ++j)
                    acc[i][j] = fmaf(a[i], bv[j], acc[i][j]);
        }
        __syncthreads();
    }

    float bb[8];
    *(float4*)&bb[0] = *(const float4*)&bias[N0 + tc * 8];
    *(float4*)&bb[4] = *(const float4*)&bias[N0 + tc * 8 + 4];
#pragma unroll
    for (int i = 0; i < 8; ++i) {
        const size_t row = (size_t)(M0 + tr * 8 + i);
        float o[8];
#pragma unroll
        for (int j = 0; j < 8; ++j) o[j] = acc[i][j] + bb[j];
        *(float4*)&xp[row * H_ + N0 + tc * 8] = *(float4*)&o[0];
        *(float4*)&xp[row * H_ + N0 + tc * 8 + 4] = *(float4*)&o[4];
    }
}

// ---------------------------------------------------------------------------
// Kernel 2: recurrence, 1024-thread redesign. 64 blocks (1/batch), 16 waves.
// R1-R6 lesson: with 512-thr blocks the allocator pins VGPR target at ~84-88
// and spills/remats the weight set (128 floats/thread) to scratch, making the
// kernel L2/L1-stream-bound (~1900 cyc/step). Weights can ONLY be fed from
// VGPRs (FMA needs 1.5 KB/cyc; LDS peaks ~0.1 KB/cyc/CU). So: shrink the ask
// to 64 floats/thread (16 named float4s), pin them INSIDE the loop (hot uses
// -> max spill weight; spilling would cost 16 reloads/iter), and set
// amdgpu_waves_per_eu(4,4) (= exactly the 4 waves/SIMD a 1024-thr block
// gives; VGPR cap 128, no incentive to shrink below it).
//
// Layout: wave w owns k-chunk [16w,16w+16); lane l owns cols j0=4l..4l+3.
//   phase1: 4 broadcast ds_read_b128 (h) -> 64 fmaf -> 1 contiguous
//           ds_write_b128 (partial row w) -> barrier
//   phase2: thread (q=l&3, jj=16w+(l>>2)) sums rows {q,4+q,8+q,12+q} col jj
//           (stride-264 layout => every instr exactly 2-way banked = free),
//           folds q via shfl_xor 1,2 (DPP/VALU), q==0 lane does xp+tanh,
//           writes h_lds[jj] + global row t -> barrier.
// ---------------------------------------------------------------------------
typedef float f4 __attribute__((ext_vector_type(4)));

__global__ __launch_bounds__(1024) __attribute__((amdgpu_waves_per_eu(4, 4)))
void rnn_kernel(const float* __restrict__ Whh, float* __restrict__ io) {
    __shared__ float h_lds[H_];
    __shared__ float part[16 * 264];  // 16 rows, stride 264 (264%32=8 -> 2-way)

    const int tid = threadIdx.x;
    const int b = blockIdx.x;
    const int w = tid >> 6;            // wave id = k-chunk [16w, 16w+16)
    const int l = tid & 63;
    const int j0 = l * 4;              // 4 columns per lane
    const int q = l & 3;               // phase2: row-quarter
    const int jj = w * 16 + (l >> 2);  // phase2: column finalized when q==0

    // 16 rows x 4 cols of Whh as named float4 SSA values (64 VGPRs).
    const float* wb = &Whh[(size_t)(w * 16) * H_ + j0];
#define LDW(K) f4 wv##K = *(const f4*)(wb + K * H_);
    LDW(0)  LDW(1)  LDW(2)  LDW(3)  LDW(4)  LDW(5)  LDW(6)  LDW(7)
    LDW(8)  LDW(9)  LDW(10) LDW(11) LDW(12) LDW(13) LDW(14) LDW(15)
#undef LDW

    float* row_base = io + (size_t)b * T_ * H_;
    float xp0 = 0.f, xp1 = 0.f;
    if (q == 0) {
        xp0 = row_base[jj];
        xp1 = row_base[H_ + jj];
    }
    if (tid < H_) h_lds[tid] = 0.f;
    __syncthreads();

    for (int t = 0; t < T_; ++t) {
        // depth-2 xp prefetch (q==0 lanes; 16 consecutive floats per wave)
        float xp2 = 0.f;
        if (q == 0 && (t + 2) < T_) xp2 = row_base[(size_t)(t + 2) * H_ + jj];

        // In-loop pin: weight regs are live-through-asm every iteration ->
        // spilling them costs 16 reloads/iter in regalloc's own model.
        asm volatile("" : "+v"(wv0), "+v"(wv1), "+v"(wv2),  "+v"(wv3),
                          "+v"(wv4), "+v"(wv5), "+v"(wv6),  "+v"(wv7),
                          "+v"(wv8), "+v"(wv9), "+v"(wv10), "+v"(wv11),
                          "+v"(wv12), "+v"(wv13), "+v"(wv14), "+v"(wv15));

        // ---- phase 1: acc[c] = sum_{kk<16} h[16w+kk] * Whh[16w+kk][j0+c]
        const f4* h4 = (const f4*)h_lds;
        const f4 ha = h4[w * 4 + 0];  // wave-uniform addr -> LDS broadcast
        const f4 hb = h4[w * 4 + 1];
        const f4 hc = h4[w * 4 + 2];
        const f4 hd = h4[w * 4 + 3];

        f4 acc = wv0 * ha.x;
        acc += wv1  * ha.y;  acc += wv2  * ha.z;  acc += wv3  * ha.w;
        acc += wv4  * hb.x;  acc += wv5  * hb.y;  acc += wv6  * hb.z;  acc += wv7  * hb.w;
        acc += wv8  * hc.x;  acc += wv9  * hc.y;  acc += wv10 * hc.z;  acc += wv11 * hc.w;
        acc += wv12 * hd.x;  acc += wv13 * hd.y;  acc += wv14 * hd.z;  acc += wv15 * hd.w;

        // one contiguous 1KB ds_write_b128 per wave
        *(f4*)&part[w * 264 + l * 4] = acc;
        __syncthreads();

        // ---- phase 2: sum 16 rows for col jj (4 reads here + xor1/xor2 fold)
        float s = 0.f;
#pragma unroll
        for (int r = 0; r < 4; ++r) s += part[(r * 4 + q) * 264 + jj];
        s += __shfl_xor(s, 1, 64);
        s += __shfl_xor(s, 2, 64);
        if (q == 0) {
            const float h = tanhf(s + xp0);
            h_lds[jj] = h;
            row_base[(size_t)t * H_ + jj] = h;
            xp0 = xp1;
            xp1 = xp2;
        }
        __syncthreads();
    }
}

// ---------------------------------------------------------------------------
extern "C" void kernel_launch(void* const* d_in, const int* in_sizes, int n_in,
                              void* d_out, int out_size, void* d_ws, size_t ws_size,
                              hipStream_t stream) {
    const float* x    = (const float*)d_in[0];
    const float* Wxh  = (const float*)d_in[1];
    const float* Whh  = (const float*)d_in[2];
    const float* bias = (const float*)d_in[3];
    float* out = (float*)d_out;

    dim3 pgrid((B_ * T_) / PM, H_ / PN);  // 1024 x 2
    proj_kernel<<<pgrid, dim3(256), 0, stream>>>(x, Wxh, bias, out);
    rnn_kernel<<<dim3(B_), dim3(1024), 0, stream>>>(Whh, out);
}